// Round 17
// baseline (814.385 us; speedup 1.0000x reference)
//
#include <hip/hip_runtime.h>
#include <math.h>

#define NXC 256
#define NQC 256
#define NUC 64
#define NHC 512
#define BR  32768
#define EPSC 1e-3f
#define NAUG 768
#define CVTB 1536

typedef _Float16 h2_t __attribute__((ext_vector_type(2)));
typedef _Float16 f16x8 __attribute__((ext_vector_type(8)));
typedef float f32x4 __attribute__((ext_vector_type(4)));
union h2u { h2_t h; unsigned int u; };

__device__ __forceinline__ h2_t pk_f16(float a, float b) {
#if __has_builtin(__builtin_amdgcn_cvt_pkrtz)
  return __builtin_bit_cast(h2_t, __builtin_amdgcn_cvt_pkrtz(a, b));
#else
  h2_t r; r.x = (_Float16)a; r.y = (_Float16)b; return r;
#endif
}
__device__ __forceinline__ unsigned int pk_bits(float a, float b) { h2u x; x.h = pk_f16(a, b); return x.u; }
__device__ __forceinline__ h2_t b2h(unsigned int u) { h2u x; x.u = u; return x.h; }
__device__ __forceinline__ unsigned int h2b(h2_t v) { h2u x; x.h = v; return x.u; }

__device__ __forceinline__ float fdot2f(h2_t a, h2_t b, float c) {
#if __has_builtin(__builtin_amdgcn_fdot2)
  return __builtin_amdgcn_fdot2(a, b, c, false);
#else
  return c + (float)a.x * (float)b.x + (float)a.y * (float)b.y;
#endif
}

__device__ __forceinline__ float fast_tanh(float x) {
  float ax = fabsf(x);
  float e  = __expf(-2.0f * ax);
  float r  = __fdividef(1.0f - e, 1.0f + e);
  return copysignf(r, x);
}

__device__ __forceinline__ float fast_rcp(float x) {
#if __has_builtin(__builtin_amdgcn_rcpf)
  return __builtin_amdgcn_rcpf(x);
#else
  return 1.0f / x;
#endif
}

// in-register GJ inversion of a 32x32 block, one row per lane (lanes 0..31; 32..63
// mirror harmlessly). Verified rounds 9/14/15.
__device__ __forceinline__ void inv32_wave(float r[32], int ii) {
#pragma unroll
  for (int k = 0; k < 32; ++k) {
    float rk[32];
#pragma unroll
    for (int j = 0; j < 32; ++j) rk[j] = __shfl(r[j], k);
    float d = fast_rcp(rk[k]);
    float fik = r[k];
    if (ii == k) {
#pragma unroll
      for (int j = 0; j < 32; ++j) r[j] = (j == k) ? d : rk[j] * d;
    } else {
#pragma unroll
      for (int j = 0; j < 32; ++j) r[j] = (j == k) ? (-fik * d) : (r[j] - fik * (d * rk[j]));
    }
  }
}

// ---------------- H and P SYRKs via f16 MFMA + fused fp32->f16 batch convert -------
// Blocks 0..39: SYRK work. Blocks 40..: grid-stride convert of xi,u to f16.
__global__ __launch_bounds__(256) void syrk_mfma_kernel(const float* __restrict__ Xin,
                                                        const float* __restrict__ Pstar,
                                                        float* __restrict__ Hm,
                                                        float* __restrict__ Naug,
                                                        const float* __restrict__ xi,
                                                        const float* __restrict__ u,
                                                        _Float16* __restrict__ xi16,
                                                        _Float16* __restrict__ u16) {
  __shared__ _Float16 Alds[128][72];
  __shared__ _Float16 Blds[64][72];
  const int b = blockIdx.x, t = threadIdx.x;
  if (b >= 40) {
    const int nxi = BR * NXC / 8, ntot = nxi + BR * NUC / 8;
    int idx = (b - 40) * 256 + t;
    int stride = CVTB * 256;
    for (int i = idx; i < ntot; i += stride) {
      const float* s; _Float16* d; int j;
      if (i < nxi) { s = xi; d = xi16; j = i; } else { s = u; d = u16; j = i - nxi; }
      float4 a = ((const float4*)s)[(size_t)j * 2];
      float4 bb = ((const float4*)s)[(size_t)j * 2 + 1];
      uint4 o;
      o.x = pk_bits(a.x, a.y);  o.y = pk_bits(a.z, a.w);
      o.z = pk_bits(bb.x, bb.y); o.w = pk_bits(bb.z, bb.w);
      ((uint4*)d)[j] = o;
    }
    return;
  }
  const float* src; float* dst; int n, K; float scale; int rowbase, colbase;
  if (b < 32) { src = Xin;   dst = Hm;   n = NHC;  K = NHC; scale = 1.0f; rowbase = (b >> 3) * 128; colbase = (b & 7) * 64; }
  else { int b2 = b - 32; src = Pstar; dst = Naug; n = NAUG; K = NXC; scale = 0.5f; rowbase = (b2 >> 2) * 128; colbase = (b2 & 3) * 64; }
  const int r_a = t >> 1, h_a = t & 1;
  const int r_b = t >> 2, q_b = t & 3;
  const int lane = t & 63, wv = t >> 6;
  const int wm = wv >> 1, wn = wv & 1;
  const int l15 = lane & 15, l4 = lane >> 4;
  f32x4 acc[4][2] = {};
  for (int k0 = 0; k0 < K; k0 += 64) {
    uint4 av[4], bvv[2];
    {
      const float* p = src + (size_t)(rowbase + r_a) * K + k0 + h_a * 32;
#pragma unroll
      for (int m = 0; m < 4; m++) {
        float4 x0 = *(const float4*)(p + m * 8);
        float4 x1 = *(const float4*)(p + m * 8 + 4);
        uint4 pk;
        pk.x = pk_bits(x0.x, x0.y); pk.y = pk_bits(x0.z, x0.w);
        pk.z = pk_bits(x1.x, x1.y); pk.w = pk_bits(x1.z, x1.w);
        av[m] = pk;
      }
    }
    {
      const float* p = src + (size_t)(colbase + r_b) * K + k0 + q_b * 16;
      float4 x0 = *(const float4*)p,       x1 = *(const float4*)(p + 4);
      float4 x2 = *(const float4*)(p + 8), x3 = *(const float4*)(p + 12);
      bvv[0].x = pk_bits(x0.x, x0.y); bvv[0].y = pk_bits(x0.z, x0.w);
      bvv[0].z = pk_bits(x1.x, x1.y); bvv[0].w = pk_bits(x1.z, x1.w);
      bvv[1].x = pk_bits(x2.x, x2.y); bvv[1].y = pk_bits(x2.z, x2.w);
      bvv[1].z = pk_bits(x3.x, x3.y); bvv[1].w = pk_bits(x3.z, x3.w);
    }
    __syncthreads();
#pragma unroll
    for (int m = 0; m < 4; m++) *(uint4*)&Alds[r_a][h_a * 32 + m * 8] = av[m];
    *(uint4*)&Blds[r_b][q_b * 16]     = bvv[0];
    *(uint4*)&Blds[r_b][q_b * 16 + 8] = bvv[1];
    __syncthreads();
#pragma unroll
    for (int ks = 0; ks < 2; ks++) {
      f16x8 af[4], bf[2];
#pragma unroll
      for (int fm = 0; fm < 4; fm++)
        af[fm] = *(const f16x8*)&Alds[wm * 64 + fm * 16 + l15][ks * 32 + l4 * 8];
#pragma unroll
      for (int fn = 0; fn < 2; fn++)
        bf[fn] = *(const f16x8*)&Blds[wn * 32 + fn * 16 + l15][ks * 32 + l4 * 8];
#pragma unroll
      for (int fm = 0; fm < 4; fm++)
#pragma unroll
        for (int fn = 0; fn < 2; fn++)
          acc[fm][fn] = __builtin_amdgcn_mfma_f32_16x16x32_f16(af[fm], bf[fn], acc[fm][fn], 0, 0, 0);
    }
  }
#pragma unroll
  for (int fm = 0; fm < 4; fm++)
#pragma unroll
    for (int fn = 0; fn < 2; fn++) {
      int col = colbase + wn * 32 + fn * 16 + l15;
      f32x4 a = acc[fm][fn];
#pragma unroll
      for (int reg = 0; reg < 4; reg++) {
        int row = rowbase + wm * 64 + fm * 16 + l4 * 4 + reg;
        float val = scale * a[reg] + ((row == col) ? EPSC : 0.f);
        dst[(size_t)row * n + col] = val;
      }
    }
}

// ---------------- derived small matrices (+ f16 weights + packed D11 pairs) --------
__global__ __launch_bounds__(256) void derive_kernel(const float* __restrict__ H,
                                                     const float* __restrict__ Y1,
                                                     const float* __restrict__ Chi,
                                                     const float* __restrict__ D12,
                                                     const float* __restrict__ B2,
                                                     float* __restrict__ Naug,
                                                     unsigned int* __restrict__ dpk_g,
                                                     _Float16* __restrict__ C1h,
                                                     _Float16* __restrict__ D12h,
                                                     _Float16* __restrict__ B2h) {
  int i = blockIdx.x, j = threadIdx.x;
  float li = 2.0f / H[(size_t)(NXC + i) * NHC + NXC + i];
  Naug[(size_t)i * NAUG + NXC + j]     = -0.5f * (H[(size_t)i * NHC + j] + Y1[i * NXC + j] - Y1[j * NXC + i]);
  C1h[i * NXC + j] = (_Float16)(li * Chi[j * NQC + i]);
  Naug[(size_t)i * NAUG + 2 * NXC + j] = -H[(size_t)i * NHC + NXC + j] - Chi[i * NQC + j];
  float dv = (j < i) ? (-li * H[(size_t)(NXC + i) * NHC + NXC + j]) : 0.f;
  float dhi = __shfl_xor(dv, 1);
  if ((j & 1) == 0) dpk_g[(size_t)(j >> 1) * NXC + i] = pk_bits(dv, dhi);
  if (j < NUC) {
    D12h[i * NUC + j] = (_Float16)D12[i * NUC + j];
    B2h[i * NUC + j]  = (_Float16)B2[i * NUC + j];
  }
}

// ---------------- GJ step v2: 128 blocks x 2 rows, coef prefetch (r13-verified) ----
__global__ __launch_bounds__(256) void gjstep_kernel(const float* __restrict__ Nin,
                                                     float* __restrict__ Nout,
                                                     _Float16* __restrict__ Ah,
                                                     _Float16* __restrict__ B1h,
                                                     int k0) {
  __shared__ float Dl[32][33];
  __shared__ float cfl[2][33];
  const int t = threadIdx.x;
  const int row0 = blockIdx.x * 2;
  const bool last = (k0 + 32 == NXC);
  // coef threads (64..127) prefetch their row's f-vector while wave0 inverts
  const bool docoef = (t >= 64 && t < 128);
  const int crr = (t - 64) >> 5, cs = t & 31;
  const int ci = row0 + crr;
  const bool cpiv = (ci >= k0 && ci < k0 + 32);
  float fv[32];
  if (docoef && !cpiv) {
#pragma unroll
    for (int q = 0; q < 32; ++q) fv[q] = Nin[(size_t)ci * NAUG + k0 + q];
  }
  if (t < 64) {
    const int ii = t & 31;
    float r[32];
#pragma unroll
    for (int j = 0; j < 32; ++j) r[j] = Nin[(size_t)(k0 + ii) * NAUG + k0 + j];
    inv32_wave(r, ii);
    if (t < 32) {
#pragma unroll
      for (int j = 0; j < 32; ++j) Dl[ii][j] = r[j];
    }
  }
  __syncthreads();
  if (docoef) {
    float c;
    if (cpiv) {
      c = Dl[ci - k0][cs];
    } else {
      float g = 0.f;
#pragma unroll
      for (int q = 0; q < 32; ++q) g = fmaf(fv[q], Dl[q][cs], g);
      c = -g;
    }
    cfl[crr][cs] = c;
  }
  __syncthreads();
  const int rr = t >> 7;                  // 0..1 (128 threads per row)
  const int i = row0 + rr;
  const bool piv = (i >= k0 && i < k0 + 32);
  float cf[32];
#pragma unroll
  for (int s = 0; s < 32; ++s) cf[s] = cfl[rr][s];
  const int c40 = (k0 + 32) >> 2;
  for (int c4 = c40 + (t & 127); c4 < (NAUG >> 2); c4 += 128) {
    float4 acc;
    if (piv) { acc.x = 0.f; acc.y = 0.f; acc.z = 0.f; acc.w = 0.f; }
    else     { acc = *(const float4*)&Nin[(size_t)i * NAUG + c4 * 4]; }
#pragma unroll
    for (int s = 0; s < 32; ++s) {
      float4 pv = *(const float4*)&Nin[(size_t)(k0 + s) * NAUG + c4 * 4];
      acc.x = fmaf(cf[s], pv.x, acc.x);
      acc.y = fmaf(cf[s], pv.y, acc.y);
      acc.z = fmaf(cf[s], pv.z, acc.z);
      acc.w = fmaf(cf[s], pv.w, acc.w);
    }
    if (!last) {
      *(float4*)&Nout[(size_t)i * NAUG + c4 * 4] = acc;
    } else {
      int cc = c4 * 4 - NXC;  // 0..511 within [A | B1]
      h2_t h0, h1;
      h0.x = (_Float16)acc.x; h0.y = (_Float16)acc.y;
      h1.x = (_Float16)acc.z; h1.y = (_Float16)acc.w;
      uint2 o; o.x = h2b(h0); o.y = h2b(h1);
      if (cc < NXC) *(uint2*)&Ah[(size_t)i * NXC + cc]          = o;
      else          *(uint2*)&B1h[(size_t)i * NXC + (cc - NXC)] = o;
    }
  }
}

// ======== wrec v19: r13 body + lane-parallel serial tri-dot =======================
// The serial phase's tri-dot was computed redundantly by all 4 threads sharing a row
// (s = t&3 only used for the wlds write). Now thread s computes quad q=s only and the
// 4 partial sums reduce via shfl_xor(1)/(2) within the row group. Over-read quads are
// zero (strict-lower-tri D11, zero-padded in derive) -- same masking as before.
__global__ __launch_bounds__(256, 2) void wrec_fused_kernel(
    const _Float16* __restrict__ xi16, const _Float16* __restrict__ u16,
    const _Float16* __restrict__ C1h, const _Float16* __restrict__ D12h,
    const float* __restrict__ bv, const unsigned int* __restrict__ dpk_g,
    const _Float16* __restrict__ Ah, const _Float16* __restrict__ B1h,
    const _Float16* __restrict__ B2h, const float* __restrict__ bx,
    float* __restrict__ out) {
  __shared__ unsigned int pool[14976];            // 59904 B
  unsigned int* wlds  = pool;                     // 64*132 u32 (w f16 pairs)
  unsigned int* dpkT  = pool + 8448;              // 32*116
  unsigned int* tript = pool + 12160;             // 32*16
  float*        vbuf  = (float*)(pool + 12672);   // 64*36

  const int t = threadIdx.x;
  const int r = t >> 2, s = t & 3;
  const int lane = t & 63, w = t >> 6;
  const int l15 = lane & 15, l4 = lane >> 4;
  const size_t rowbase = (size_t)blockIdx.x * 64;
  const _Float16* wl16 = (const _Float16*)wlds;

  // preload this wave's xi/u A-fragments (rows w*16 + l15)
  f16x8 xi_frag[8], u_frag[2];
  {
    const _Float16* px = xi16 + (rowbase + w * 16 + l15) * NXC + l4 * 8;
#pragma unroll
    for (int kc = 0; kc < 8; ++kc) xi_frag[kc] = *(const f16x8*)(px + kc * 32);
    const _Float16* pu = u16 + (rowbase + w * 16 + l15) * NUC + l4 * 8;
#pragma unroll
    for (int kc = 0; kc < 2; ++kc) u_frag[kc] = *(const f16x8*)(pu + kc * 32);
  }

  h2_t wpk[16];
#pragma unroll
  for (int p = 0; p < 16; ++p) wpk[p] = pk_f16(0.f, 0.f);

  for (int kb = 0; kb < 8; ++kb) {
    const int i0 = kb * 32;
    for (int idx = t; idx < (i0 >> 1) * 32; idx += 256) {
      int cc = idx & 31, jp = idx >> 5;
      dpkT[cc * 116 + jp] = dpk_g[(size_t)jp * NXC + i0 + cc];
    }
    if (t < 128) {
      int jp = t >> 3, iq = t & 7;
      uint4 d4 = *(const uint4*)&dpk_g[(size_t)(i0 / 2 + jp) * NXC + i0 + iq * 4];
      tript[(iq * 4 + 0) * 16 + jp] = d4.x;
      tript[(iq * 4 + 1) * 16 + jp] = d4.y;
      tript[(iq * 4 + 2) * 16 + jp] = d4.z;
      tript[(iq * 4 + 3) * 16 + jp] = d4.w;
    }
    // v_base: acc = bv + xi@C1^T + u@D12^T (per-wave, fp32 kept)
    f32x4 acc0, acc1;
    {
      float b0 = bv[i0 + l15], b1 = bv[i0 + 16 + l15];
      acc0[0] = b0; acc0[1] = b0; acc0[2] = b0; acc0[3] = b0;
      acc1[0] = b1; acc1[1] = b1; acc1[2] = b1; acc1[3] = b1;
#pragma unroll
      for (int kc = 0; kc < 8; ++kc) {
        f16x8 bf0 = *(const f16x8*)&C1h[(size_t)(i0 + l15) * NXC + kc * 32 + l4 * 8];
        f16x8 bf1 = *(const f16x8*)&C1h[(size_t)(i0 + 16 + l15) * NXC + kc * 32 + l4 * 8];
        acc0 = __builtin_amdgcn_mfma_f32_16x16x32_f16(xi_frag[kc], bf0, acc0, 0, 0, 0);
        acc1 = __builtin_amdgcn_mfma_f32_16x16x32_f16(xi_frag[kc], bf1, acc1, 0, 0, 0);
      }
#pragma unroll
      for (int kc = 0; kc < 2; ++kc) {
        f16x8 bf0 = *(const f16x8*)&D12h[(size_t)(i0 + l15) * NUC + kc * 32 + l4 * 8];
        f16x8 bf1 = *(const f16x8*)&D12h[(size_t)(i0 + 16 + l15) * NUC + kc * 32 + l4 * 8];
        acc0 = __builtin_amdgcn_mfma_f32_16x16x32_f16(u_frag[kc], bf0, acc0, 0, 0, 0);
        acc1 = __builtin_amdgcn_mfma_f32_16x16x32_f16(u_frag[kc], bf1, acc1, 0, 0, 0);
      }
    }
    __syncthreads();

    // cross terms from previous kb blocks
    for (int ks = 0; ks < kb; ++ks) {
      f16x8 af = *(const f16x8*)&wl16[(size_t)(w * 16 + l15) * 264 + ks * 32 + l4 * 8];
      uint4 b0 = *(const uint4*)&dpkT[(l15) * 116 + ks * 16 + l4 * 4];
      uint4 b1 = *(const uint4*)&dpkT[(16 + l15) * 116 + ks * 16 + l4 * 4];
      acc0 = __builtin_amdgcn_mfma_f32_16x16x32_f16(af, __builtin_bit_cast(f16x8, b0), acc0, 0, 0, 0);
      acc1 = __builtin_amdgcn_mfma_f32_16x16x32_f16(af, __builtin_bit_cast(f16x8, b1), acc1, 0, 0, 0);
    }

#pragma unroll
    for (int reg = 0; reg < 4; ++reg) {
      int rowm = w * 16 + l4 * 4 + reg;
      vbuf[rowm * 36 + l15]      = acc0[reg];
      vbuf[rowm * 36 + 16 + l15] = acc1[reg];
    }

    float wprev = 0.f;
#pragma unroll
    for (int i = 0; i < 32; ++i) {
      const int npairs = (i + 1) >> 1;
      const int nq = (npairs + 3) >> 2;
      float td = 0.f;
      if (s < nq) {
        uint4 tq = *(const uint4*)&tript[i * 16 + s * 4];
        float t0 = 0.f, t1 = 0.f;
        t0 = fdot2f(wpk[s * 4 + 0], b2h(tq.x), t0);
        t1 = fdot2f(wpk[s * 4 + 1], b2h(tq.y), t1);
        t0 = fdot2f(wpk[s * 4 + 2], b2h(tq.z), t0);
        t1 = fdot2f(wpk[s * 4 + 3], b2h(tq.w), t1);
        td = t0 + t1;
      }
      td += __shfl_xor(td, 1);
      td += __shfl_xor(td, 2);
      float vi = vbuf[r * 36 + i];
      float wi = fast_tanh(vi + td);
      if ((i & 1) == 0) { wprev = wi; wpk[i >> 1] = pk_f16(wi, 0.f); }
      else              { wpk[i >> 1] = pk_f16(wprev, wi); }
    }

    {
      uint4 o;
      o.x = h2b(wpk[s * 4 + 0]); o.y = h2b(wpk[s * 4 + 1]);
      o.z = h2b(wpk[s * 4 + 2]); o.w = h2b(wpk[s * 4 + 3]);
      *(uint4*)&wlds[r * 132 + kb * 16 + s * 4] = o;
    }
    __syncthreads();
  }

  // ---- final fused GEMM: out = xi@Ah^T + w@B1h^T + u@B2h^T + bx ----
  _Float16* Ws = (_Float16*)dpkT;
  f32x4 oacc[16];
#pragma unroll
  for (int ct = 0; ct < 16; ++ct) {
    float bb = bx[ct * 16 + l15];
    oacc[ct][0] = bb; oacc[ct][1] = bb; oacc[ct][2] = bb; oacc[ct][3] = bb;
  }
  uint4 pa, pb, pc, pd;
  {
    const _Float16* p = Ah + (size_t)t * NXC;   // rr=0: Ah, kc=0
    pa = *(const uint4*)p;        pb = *(const uint4*)(p + 8);
    pc = *(const uint4*)(p + 16); pd = *(const uint4*)(p + 24);
  }
#pragma unroll
  for (int rr = 0; rr < 18; ++rr) {
    const int sel = rr < 8 ? 0 : (rr < 16 ? 1 : 2);
    const int kc  = sel == 0 ? rr : (sel == 1 ? rr - 8 : rr - 16);
    __syncthreads();                       // readers of previous chunk done
    *(uint4*)&Ws[t * 40]      = pa;
    *(uint4*)&Ws[t * 40 + 8]  = pb;
    *(uint4*)&Ws[t * 40 + 16] = pc;
    *(uint4*)&Ws[t * 40 + 24] = pd;
    __syncthreads();                       // chunk visible
    if (rr < 17) {                         // T14: issue next chunk early
      const int rs = rr + 1;
      const int s2 = rs < 8 ? 0 : (rs < 16 ? 1 : 2);
      const int k2 = s2 == 0 ? rs : (s2 == 1 ? rs - 8 : rs - 16);
      const _Float16* Wp = s2 == 0 ? Ah : (s2 == 1 ? B1h : B2h);
      const int KK = (s2 == 2) ? NUC : NXC;
      const _Float16* p = Wp + (size_t)t * KK + k2 * 32;
      pa = *(const uint4*)p;        pb = *(const uint4*)(p + 8);
      pc = *(const uint4*)(p + 16); pd = *(const uint4*)(p + 24);
    }
    f16x8 af;
    if (sel == 0)      af = xi_frag[kc];
    else if (sel == 1) af = *(const f16x8*)&wl16[(size_t)(w * 16 + l15) * 264 + kc * 32 + l4 * 8];
    else               af = u_frag[kc];
#pragma unroll
    for (int ct = 0; ct < 16; ++ct) {
      f16x8 bf = *(const f16x8*)&Ws[(ct * 16 + l15) * 40 + l4 * 8];
      oacc[ct] = __builtin_amdgcn_mfma_f32_16x16x32_f16(af, bf, oacc[ct], 0, 0, 0);
    }
  }
#pragma unroll
  for (int ct = 0; ct < 16; ++ct) {
#pragma unroll
    for (int reg = 0; reg < 4; ++reg) {
      int row = (int)rowbase + w * 16 + l4 * 4 + reg;
      out[(size_t)row * NXC + ct * 16 + l15] = oacc[ct][reg];
    }
  }
}

extern "C" void kernel_launch(void* const* d_in, const int* in_sizes, int n_in,
                              void* d_out, int out_size, void* d_ws, size_t ws_size,
                              hipStream_t stream) {
  (void)in_sizes; (void)n_in; (void)out_size; (void)ws_size;
  const float* xi    = (const float*)d_in[1];
  const float* u     = (const float*)d_in[2];
  const float* Pstar = (const float*)d_in[3];
  const float* Chi   = (const float*)d_in[4];
  const float* Y1    = (const float*)d_in[5];
  const float* B2    = (const float*)d_in[6];
  const float* D12   = (const float*)d_in[7];
  const float* Xin   = (const float*)d_in[8];
  const float* bx    = (const float*)d_in[9];
  const float* bv    = (const float*)d_in[10];
  float* out = (float*)d_out;

  float* ws = (float*)d_ws;
  _Float16* xi16 = (_Float16*)ws;                       // BR*NXC f16
  _Float16* u16  = xi16 + (size_t)BR * NXC;             // BR*NUC f16
  float* Hm = (float*)(u16 + (size_t)BR * NUC);         // 512*512
  float* NA = Hm + (size_t)NHC * NHC;                   // 256*768 augmented [P|Y|Z], ping
  float* NB = NA + (size_t)NXC * NAUG;                  // 256*768 pong
  unsigned int* dpkg = (unsigned int*)(NB + (size_t)NXC * NAUG);   // 128*256 u32
  _Float16* C1h  = (_Float16*)(dpkg + 128 * 256);
  _Float16* D12h = C1h + (size_t)NQC * NXC;
  _Float16* Ah   = D12h + (size_t)NQC * NUC;
  _Float16* B1h  = Ah + (size_t)NXC * NXC;
  _Float16* B2h  = B1h + (size_t)NXC * NQC;

  // setup: SYRKs + fused xi/u f16 convert in ONE launch (blocks 40.. do the cvt)
  syrk_mfma_kernel<<<40 + CVTB, 256, 0, stream>>>(Xin, Pstar, Hm, NA, xi, u, xi16, u16);
  derive_kernel<<<NXC, NXC, 0, stream>>>(Hm, Y1, Chi, D12, B2, NA, dpkg, C1h, D12h, B2h);

  // blocked Gauss-Jordan on augmented [P|Y|Z], 32-wide pivots, 128 blocks x 2 rows
  for (int kb = 0; kb < 8; ++kb) {
    const float* Nin = (kb & 1) ? NB : NA;
    float*      Nout = (kb & 1) ? NA : NB;
    gjstep_kernel<<<128, 256, 0, stream>>>(Nin, Nout, Ah, B1h, kb * 32);
  }

  // fully fused batch phase: v_base + w recurrence + xi_dot in one kernel
  wrec_fused_kernel<<<BR / 64, 256, 0, stream>>>(
      xi16, u16, C1h, D12h, bv, dpkg, Ah, B1h, B2h, bx, out);
}

// Round 18
// 250.890 us; speedup vs baseline: 3.2460x; 3.2460x over previous
//
#include <hip/hip_runtime.h>
#include <math.h>

#define NXC 256
#define NQC 256
#define NUC 64
#define NHC 512
#define BR  32768
#define EPSC 1e-3f
#define NAUG 768
#define CVTB 1536

typedef _Float16 h2_t __attribute__((ext_vector_type(2)));
typedef _Float16 f16x8 __attribute__((ext_vector_type(8)));
typedef float f32x4 __attribute__((ext_vector_type(4)));
union h2u { h2_t h; unsigned int u; };

__device__ __forceinline__ h2_t pk_f16(float a, float b) {
#if __has_builtin(__builtin_amdgcn_cvt_pkrtz)
  return __builtin_bit_cast(h2_t, __builtin_amdgcn_cvt_pkrtz(a, b));
#else
  h2_t r; r.x = (_Float16)a; r.y = (_Float16)b; return r;
#endif
}
__device__ __forceinline__ unsigned int pk_bits(float a, float b) { h2u x; x.h = pk_f16(a, b); return x.u; }
__device__ __forceinline__ h2_t b2h(unsigned int u) { h2u x; x.u = u; return x.h; }
__device__ __forceinline__ unsigned int h2b(h2_t v) { h2u x; x.h = v; return x.u; }

__device__ __forceinline__ float fdot2f(h2_t a, h2_t b, float c) {
#if __has_builtin(__builtin_amdgcn_fdot2)
  return __builtin_amdgcn_fdot2(a, b, c, false);
#else
  return c + (float)a.x * (float)b.x + (float)a.y * (float)b.y;
#endif
}

__device__ __forceinline__ float fast_tanh(float x) {
  float ax = fabsf(x);
  float e  = __expf(-2.0f * ax);
  float r  = __fdividef(1.0f - e, 1.0f + e);
  return copysignf(r, x);
}

__device__ __forceinline__ float fast_rcp(float x) {
#if __has_builtin(__builtin_amdgcn_rcpf)
  return __builtin_amdgcn_rcpf(x);
#else
  return 1.0f / x;
#endif
}

// in-register GJ inversion of a 32x32 block, one row per lane (lanes 0..31; 32..63
// mirror harmlessly). Verified rounds 9/14/15.
__device__ __forceinline__ void inv32_wave(float r[32], int ii) {
#pragma unroll
  for (int k = 0; k < 32; ++k) {
    float rk[32];
#pragma unroll
    for (int j = 0; j < 32; ++j) rk[j] = __shfl(r[j], k);
    float d = fast_rcp(rk[k]);
    float fik = r[k];
    if (ii == k) {
#pragma unroll
      for (int j = 0; j < 32; ++j) r[j] = (j == k) ? d : rk[j] * d;
    } else {
#pragma unroll
      for (int j = 0; j < 32; ++j) r[j] = (j == k) ? (-fik * d) : (r[j] - fik * (d * rk[j]));
    }
  }
}

// ---------------- H and P SYRKs via f16 MFMA + fused fp32->f16 batch convert -------
// Blocks 0..39: SYRK work. Blocks 40..: grid-stride convert of xi,u to f16.
__global__ __launch_bounds__(256) void syrk_mfma_kernel(const float* __restrict__ Xin,
                                                        const float* __restrict__ Pstar,
                                                        float* __restrict__ Hm,
                                                        float* __restrict__ Naug,
                                                        const float* __restrict__ xi,
                                                        const float* __restrict__ u,
                                                        _Float16* __restrict__ xi16,
                                                        _Float16* __restrict__ u16) {
  __shared__ _Float16 Alds[128][72];
  __shared__ _Float16 Blds[64][72];
  const int b = blockIdx.x, t = threadIdx.x;
  if (b >= 40) {
    const int nxi = BR * NXC / 8, ntot = nxi + BR * NUC / 8;
    int idx = (b - 40) * 256 + t;
    int stride = CVTB * 256;
    for (int i = idx; i < ntot; i += stride) {
      const float* s; _Float16* d; int j;
      if (i < nxi) { s = xi; d = xi16; j = i; } else { s = u; d = u16; j = i - nxi; }
      float4 a = ((const float4*)s)[(size_t)j * 2];
      float4 bb = ((const float4*)s)[(size_t)j * 2 + 1];
      uint4 o;
      o.x = pk_bits(a.x, a.y);  o.y = pk_bits(a.z, a.w);
      o.z = pk_bits(bb.x, bb.y); o.w = pk_bits(bb.z, bb.w);
      ((uint4*)d)[j] = o;
    }
    return;
  }
  const float* src; float* dst; int n, K; float scale; int rowbase, colbase;
  if (b < 32) { src = Xin;   dst = Hm;   n = NHC;  K = NHC; scale = 1.0f; rowbase = (b >> 3) * 128; colbase = (b & 7) * 64; }
  else { int b2 = b - 32; src = Pstar; dst = Naug; n = NAUG; K = NXC; scale = 0.5f; rowbase = (b2 >> 2) * 128; colbase = (b2 & 3) * 64; }
  const int r_a = t >> 1, h_a = t & 1;
  const int r_b = t >> 2, q_b = t & 3;
  const int lane = t & 63, wv = t >> 6;
  const int wm = wv >> 1, wn = wv & 1;
  const int l15 = lane & 15, l4 = lane >> 4;
  f32x4 acc[4][2] = {};
  for (int k0 = 0; k0 < K; k0 += 64) {
    uint4 av[4], bvv[2];
    {
      const float* p = src + (size_t)(rowbase + r_a) * K + k0 + h_a * 32;
#pragma unroll
      for (int m = 0; m < 4; m++) {
        float4 x0 = *(const float4*)(p + m * 8);
        float4 x1 = *(const float4*)(p + m * 8 + 4);
        uint4 pk;
        pk.x = pk_bits(x0.x, x0.y); pk.y = pk_bits(x0.z, x0.w);
        pk.z = pk_bits(x1.x, x1.y); pk.w = pk_bits(x1.z, x1.w);
        av[m] = pk;
      }
    }
    {
      const float* p = src + (size_t)(colbase + r_b) * K + k0 + q_b * 16;
      float4 x0 = *(const float4*)p,       x1 = *(const float4*)(p + 4);
      float4 x2 = *(const float4*)(p + 8), x3 = *(const float4*)(p + 12);
      bvv[0].x = pk_bits(x0.x, x0.y); bvv[0].y = pk_bits(x0.z, x0.w);
      bvv[0].z = pk_bits(x1.x, x1.y); bvv[0].w = pk_bits(x1.z, x1.w);
      bvv[1].x = pk_bits(x2.x, x2.y); bvv[1].y = pk_bits(x2.z, x2.w);
      bvv[1].z = pk_bits(x3.x, x3.y); bvv[1].w = pk_bits(x3.z, x3.w);
    }
    __syncthreads();
#pragma unroll
    for (int m = 0; m < 4; m++) *(uint4*)&Alds[r_a][h_a * 32 + m * 8] = av[m];
    *(uint4*)&Blds[r_b][q_b * 16]     = bvv[0];
    *(uint4*)&Blds[r_b][q_b * 16 + 8] = bvv[1];
    __syncthreads();
#pragma unroll
    for (int ks = 0; ks < 2; ks++) {
      f16x8 af[4], bf[2];
#pragma unroll
      for (int fm = 0; fm < 4; fm++)
        af[fm] = *(const f16x8*)&Alds[wm * 64 + fm * 16 + l15][ks * 32 + l4 * 8];
#pragma unroll
      for (int fn = 0; fn < 2; fn++)
        bf[fn] = *(const f16x8*)&Blds[wn * 32 + fn * 16 + l15][ks * 32 + l4 * 8];
#pragma unroll
      for (int fm = 0; fm < 4; fm++)
#pragma unroll
        for (int fn = 0; fn < 2; fn++)
          acc[fm][fn] = __builtin_amdgcn_mfma_f32_16x16x32_f16(af[fm], bf[fn], acc[fm][fn], 0, 0, 0);
    }
  }
#pragma unroll
  for (int fm = 0; fm < 4; fm++)
#pragma unroll
    for (int fn = 0; fn < 2; fn++) {
      int col = colbase + wn * 32 + fn * 16 + l15;
      f32x4 a = acc[fm][fn];
#pragma unroll
      for (int reg = 0; reg < 4; reg++) {
        int row = rowbase + wm * 64 + fm * 16 + l4 * 4 + reg;
        float val = scale * a[reg] + ((row == col) ? EPSC : 0.f);
        dst[(size_t)row * n + col] = val;
      }
    }
}

// ---------------- derived small matrices (+ f16 weights + packed D11 pairs) --------
__global__ __launch_bounds__(256) void derive_kernel(const float* __restrict__ H,
                                                     const float* __restrict__ Y1,
                                                     const float* __restrict__ Chi,
                                                     const float* __restrict__ D12,
                                                     const float* __restrict__ B2,
                                                     float* __restrict__ Naug,
                                                     unsigned int* __restrict__ dpk_g,
                                                     _Float16* __restrict__ C1h,
                                                     _Float16* __restrict__ D12h,
                                                     _Float16* __restrict__ B2h) {
  int i = blockIdx.x, j = threadIdx.x;
  float li = 2.0f / H[(size_t)(NXC + i) * NHC + NXC + i];
  Naug[(size_t)i * NAUG + NXC + j]     = -0.5f * (H[(size_t)i * NHC + j] + Y1[i * NXC + j] - Y1[j * NXC + i]);
  C1h[i * NXC + j] = (_Float16)(li * Chi[j * NQC + i]);
  Naug[(size_t)i * NAUG + 2 * NXC + j] = -H[(size_t)i * NHC + NXC + j] - Chi[i * NQC + j];
  float dv = (j < i) ? (-li * H[(size_t)(NXC + i) * NHC + NXC + j]) : 0.f;
  float dhi = __shfl_xor(dv, 1);
  if ((j & 1) == 0) dpk_g[(size_t)(j >> 1) * NXC + i] = pk_bits(dv, dhi);
  if (j < NUC) {
    D12h[i * NUC + j] = (_Float16)D12[i * NUC + j];
    B2h[i * NUC + j]  = (_Float16)B2[i * NUC + j];
  }
}

// ---------------- GJ step v2: 128 blocks x 2 rows, coef prefetch (r13-verified) ----
__global__ __launch_bounds__(256) void gjstep_kernel(const float* __restrict__ Nin,
                                                     float* __restrict__ Nout,
                                                     _Float16* __restrict__ Ah,
                                                     _Float16* __restrict__ B1h,
                                                     int k0) {
  __shared__ float Dl[32][33];
  __shared__ float cfl[2][33];
  const int t = threadIdx.x;
  const int row0 = blockIdx.x * 2;
  const bool last = (k0 + 32 == NXC);
  // coef threads (64..127) prefetch their row's f-vector while wave0 inverts
  const bool docoef = (t >= 64 && t < 128);
  const int crr = (t - 64) >> 5, cs = t & 31;
  const int ci = row0 + crr;
  const bool cpiv = (ci >= k0 && ci < k0 + 32);
  float fv[32];
  if (docoef && !cpiv) {
#pragma unroll
    for (int q = 0; q < 32; ++q) fv[q] = Nin[(size_t)ci * NAUG + k0 + q];
  }
  if (t < 64) {
    const int ii = t & 31;
    float r[32];
#pragma unroll
    for (int j = 0; j < 32; ++j) r[j] = Nin[(size_t)(k0 + ii) * NAUG + k0 + j];
    inv32_wave(r, ii);
    if (t < 32) {
#pragma unroll
      for (int j = 0; j < 32; ++j) Dl[ii][j] = r[j];
    }
  }
  __syncthreads();
  if (docoef) {
    float c;
    if (cpiv) {
      c = Dl[ci - k0][cs];
    } else {
      float g = 0.f;
#pragma unroll
      for (int q = 0; q < 32; ++q) g = fmaf(fv[q], Dl[q][cs], g);
      c = -g;
    }
    cfl[crr][cs] = c;
  }
  __syncthreads();
  const int rr = t >> 7;                  // 0..1 (128 threads per row)
  const int i = row0 + rr;
  const bool piv = (i >= k0 && i < k0 + 32);
  float cf[32];
#pragma unroll
  for (int s = 0; s < 32; ++s) cf[s] = cfl[rr][s];
  const int c40 = (k0 + 32) >> 2;
  for (int c4 = c40 + (t & 127); c4 < (NAUG >> 2); c4 += 128) {
    float4 acc;
    if (piv) { acc.x = 0.f; acc.y = 0.f; acc.z = 0.f; acc.w = 0.f; }
    else     { acc = *(const float4*)&Nin[(size_t)i * NAUG + c4 * 4]; }
#pragma unroll
    for (int s = 0; s < 32; ++s) {
      float4 pv = *(const float4*)&Nin[(size_t)(k0 + s) * NAUG + c4 * 4];
      acc.x = fmaf(cf[s], pv.x, acc.x);
      acc.y = fmaf(cf[s], pv.y, acc.y);
      acc.z = fmaf(cf[s], pv.z, acc.z);
      acc.w = fmaf(cf[s], pv.w, acc.w);
    }
    if (!last) {
      *(float4*)&Nout[(size_t)i * NAUG + c4 * 4] = acc;
    } else {
      int cc = c4 * 4 - NXC;  // 0..511 within [A | B1]
      h2_t h0, h1;
      h0.x = (_Float16)acc.x; h0.y = (_Float16)acc.y;
      h1.x = (_Float16)acc.z; h1.y = (_Float16)acc.w;
      uint2 o; o.x = h2b(h0); o.y = h2b(h1);
      if (cc < NXC) *(uint2*)&Ah[(size_t)i * NXC + cc]          = o;
      else          *(uint2*)&B1h[(size_t)i * NXC + (cc - NXC)] = o;
    }
  }
}

// ======== wrec v13b (round-13/15 verified, 250.5 us config): fused G1 + rec + G2 ===
// NOTE (r16 lesson, rule #20): the serial tri-dot MUST keep compile-time wpk indices
// (fully unrolled q-loop). Runtime-indexed wpk[s*4+j] demotes wpk to scratch: 5x slow.
__global__ __launch_bounds__(256, 2) void wrec_fused_kernel(
    const _Float16* __restrict__ xi16, const _Float16* __restrict__ u16,
    const _Float16* __restrict__ C1h, const _Float16* __restrict__ D12h,
    const float* __restrict__ bv, const unsigned int* __restrict__ dpk_g,
    const _Float16* __restrict__ Ah, const _Float16* __restrict__ B1h,
    const _Float16* __restrict__ B2h, const float* __restrict__ bx,
    float* __restrict__ out) {
  __shared__ unsigned int pool[14976];            // 59904 B
  unsigned int* wlds  = pool;                     // 64*132 u32 (w f16 pairs)
  unsigned int* dpkT  = pool + 8448;              // 32*116
  unsigned int* tript = pool + 12160;             // 32*16
  float*        vbuf  = (float*)(pool + 12672);   // 64*36

  const int t = threadIdx.x;
  const int r = t >> 2, s = t & 3;
  const int lane = t & 63, w = t >> 6;
  const int l15 = lane & 15, l4 = lane >> 4;
  const size_t rowbase = (size_t)blockIdx.x * 64;
  const _Float16* wl16 = (const _Float16*)wlds;

  // preload this wave's xi/u A-fragments (rows w*16 + l15)
  f16x8 xi_frag[8], u_frag[2];
  {
    const _Float16* px = xi16 + (rowbase + w * 16 + l15) * NXC + l4 * 8;
#pragma unroll
    for (int kc = 0; kc < 8; ++kc) xi_frag[kc] = *(const f16x8*)(px + kc * 32);
    const _Float16* pu = u16 + (rowbase + w * 16 + l15) * NUC + l4 * 8;
#pragma unroll
    for (int kc = 0; kc < 2; ++kc) u_frag[kc] = *(const f16x8*)(pu + kc * 32);
  }

  h2_t wpk[16];
#pragma unroll
  for (int p = 0; p < 16; ++p) wpk[p] = pk_f16(0.f, 0.f);

  for (int kb = 0; kb < 8; ++kb) {
    const int i0 = kb * 32;
    for (int idx = t; idx < (i0 >> 1) * 32; idx += 256) {
      int cc = idx & 31, jp = idx >> 5;
      dpkT[cc * 116 + jp] = dpk_g[(size_t)jp * NXC + i0 + cc];
    }
    if (t < 128) {
      int jp = t >> 3, iq = t & 7;
      uint4 d4 = *(const uint4*)&dpk_g[(size_t)(i0 / 2 + jp) * NXC + i0 + iq * 4];
      tript[(iq * 4 + 0) * 16 + jp] = d4.x;
      tript[(iq * 4 + 1) * 16 + jp] = d4.y;
      tript[(iq * 4 + 2) * 16 + jp] = d4.z;
      tript[(iq * 4 + 3) * 16 + jp] = d4.w;
    }
    // v_base: acc = bv + xi@C1^T + u@D12^T (per-wave, fp32 kept)
    f32x4 acc0, acc1;
    {
      float b0 = bv[i0 + l15], b1 = bv[i0 + 16 + l15];
      acc0[0] = b0; acc0[1] = b0; acc0[2] = b0; acc0[3] = b0;
      acc1[0] = b1; acc1[1] = b1; acc1[2] = b1; acc1[3] = b1;
#pragma unroll
      for (int kc = 0; kc < 8; ++kc) {
        f16x8 bf0 = *(const f16x8*)&C1h[(size_t)(i0 + l15) * NXC + kc * 32 + l4 * 8];
        f16x8 bf1 = *(const f16x8*)&C1h[(size_t)(i0 + 16 + l15) * NXC + kc * 32 + l4 * 8];
        acc0 = __builtin_amdgcn_mfma_f32_16x16x32_f16(xi_frag[kc], bf0, acc0, 0, 0, 0);
        acc1 = __builtin_amdgcn_mfma_f32_16x16x32_f16(xi_frag[kc], bf1, acc1, 0, 0, 0);
      }
#pragma unroll
      for (int kc = 0; kc < 2; ++kc) {
        f16x8 bf0 = *(const f16x8*)&D12h[(size_t)(i0 + l15) * NUC + kc * 32 + l4 * 8];
        f16x8 bf1 = *(const f16x8*)&D12h[(size_t)(i0 + 16 + l15) * NUC + kc * 32 + l4 * 8];
        acc0 = __builtin_amdgcn_mfma_f32_16x16x32_f16(u_frag[kc], bf0, acc0, 0, 0, 0);
        acc1 = __builtin_amdgcn_mfma_f32_16x16x32_f16(u_frag[kc], bf1, acc1, 0, 0, 0);
      }
    }
    __syncthreads();

    // cross terms from previous kb blocks
    for (int ks = 0; ks < kb; ++ks) {
      f16x8 af = *(const f16x8*)&wl16[(size_t)(w * 16 + l15) * 264 + ks * 32 + l4 * 8];
      uint4 b0 = *(const uint4*)&dpkT[(l15) * 116 + ks * 16 + l4 * 4];
      uint4 b1 = *(const uint4*)&dpkT[(16 + l15) * 116 + ks * 16 + l4 * 4];
      acc0 = __builtin_amdgcn_mfma_f32_16x16x32_f16(af, __builtin_bit_cast(f16x8, b0), acc0, 0, 0, 0);
      acc1 = __builtin_amdgcn_mfma_f32_16x16x32_f16(af, __builtin_bit_cast(f16x8, b1), acc1, 0, 0, 0);
    }

#pragma unroll
    for (int reg = 0; reg < 4; ++reg) {
      int rowm = w * 16 + l4 * 4 + reg;
      vbuf[rowm * 36 + l15]      = acc0[reg];
      vbuf[rowm * 36 + 16 + l15] = acc1[reg];
    }

    float wprev = 0.f;
#pragma unroll
    for (int i = 0; i < 32; ++i) {
      const int npairs = (i + 1) >> 1;
      const int nq = (npairs + 3) >> 2;
      float td0 = 0.f, td1 = 0.f;
#pragma unroll
      for (int q = 0; q < nq; ++q) {
        uint4 tq = *(const uint4*)&tript[i * 16 + q * 4];
        td0 = fdot2f(wpk[q * 4 + 0], b2h(tq.x), td0);
        td1 = fdot2f(wpk[q * 4 + 1], b2h(tq.y), td1);
        td0 = fdot2f(wpk[q * 4 + 2], b2h(tq.z), td0);
        td1 = fdot2f(wpk[q * 4 + 3], b2h(tq.w), td1);
      }
      float vi = vbuf[r * 36 + i];
      float wi = fast_tanh(vi + td0 + td1);
      if ((i & 1) == 0) { wprev = wi; wpk[i >> 1] = pk_f16(wi, 0.f); }
      else              { wpk[i >> 1] = pk_f16(wprev, wi); }
    }

    {
      uint4 o;
      o.x = h2b(wpk[s * 4 + 0]); o.y = h2b(wpk[s * 4 + 1]);
      o.z = h2b(wpk[s * 4 + 2]); o.w = h2b(wpk[s * 4 + 3]);
      *(uint4*)&wlds[r * 132 + kb * 16 + s * 4] = o;
    }
    __syncthreads();
  }

  // ---- final fused GEMM: out = xi@Ah^T + w@B1h^T + u@B2h^T + bx ----
  _Float16* Ws = (_Float16*)dpkT;
  f32x4 oacc[16];
#pragma unroll
  for (int ct = 0; ct < 16; ++ct) {
    float bb = bx[ct * 16 + l15];
    oacc[ct][0] = bb; oacc[ct][1] = bb; oacc[ct][2] = bb; oacc[ct][3] = bb;
  }
  uint4 pa, pb, pc, pd;
  {
    const _Float16* p = Ah + (size_t)t * NXC;   // rr=0: Ah, kc=0
    pa = *(const uint4*)p;        pb = *(const uint4*)(p + 8);
    pc = *(const uint4*)(p + 16); pd = *(const uint4*)(p + 24);
  }
#pragma unroll
  for (int rr = 0; rr < 18; ++rr) {
    const int sel = rr < 8 ? 0 : (rr < 16 ? 1 : 2);
    const int kc  = sel == 0 ? rr : (sel == 1 ? rr - 8 : rr - 16);
    __syncthreads();                       // readers of previous chunk done
    *(uint4*)&Ws[t * 40]      = pa;
    *(uint4*)&Ws[t * 40 + 8]  = pb;
    *(uint4*)&Ws[t * 40 + 16] = pc;
    *(uint4*)&Ws[t * 40 + 24] = pd;
    __syncthreads();                       // chunk visible
    if (rr < 17) {                         // T14: issue next chunk early
      const int rs = rr + 1;
      const int s2 = rs < 8 ? 0 : (rs < 16 ? 1 : 2);
      const int k2 = s2 == 0 ? rs : (s2 == 1 ? rs - 8 : rs - 16);
      const _Float16* Wp = s2 == 0 ? Ah : (s2 == 1 ? B1h : B2h);
      const int KK = (s2 == 2) ? NUC : NXC;
      const _Float16* p = Wp + (size_t)t * KK + k2 * 32;
      pa = *(const uint4*)p;        pb = *(const uint4*)(p + 8);
      pc = *(const uint4*)(p + 16); pd = *(const uint4*)(p + 24);
    }
    f16x8 af;
    if (sel == 0)      af = xi_frag[kc];
    else if (sel == 1) af = *(const f16x8*)&wl16[(size_t)(w * 16 + l15) * 264 + kc * 32 + l4 * 8];
    else               af = u_frag[kc];
#pragma unroll
    for (int ct = 0; ct < 16; ++ct) {
      f16x8 bf = *(const f16x8*)&Ws[(ct * 16 + l15) * 40 + l4 * 8];
      oacc[ct] = __builtin_amdgcn_mfma_f32_16x16x32_f16(af, bf, oacc[ct], 0, 0, 0);
    }
  }
#pragma unroll
  for (int ct = 0; ct < 16; ++ct) {
#pragma unroll
    for (int reg = 0; reg < 4; ++reg) {
      int row = (int)rowbase + w * 16 + l4 * 4 + reg;
      out[(size_t)row * NXC + ct * 16 + l15] = oacc[ct][reg];
    }
  }
}

extern "C" void kernel_launch(void* const* d_in, const int* in_sizes, int n_in,
                              void* d_out, int out_size, void* d_ws, size_t ws_size,
                              hipStream_t stream) {
  (void)in_sizes; (void)n_in; (void)out_size; (void)ws_size;
  const float* xi    = (const float*)d_in[1];
  const float* u     = (const float*)d_in[2];
  const float* Pstar = (const float*)d_in[3];
  const float* Chi   = (const float*)d_in[4];
  const float* Y1    = (const float*)d_in[5];
  const float* B2    = (const float*)d_in[6];
  const float* D12   = (const float*)d_in[7];
  const float* Xin   = (const float*)d_in[8];
  const float* bx    = (const float*)d_in[9];
  const float* bv    = (const float*)d_in[10];
  float* out = (float*)d_out;

  float* ws = (float*)d_ws;
  _Float16* xi16 = (_Float16*)ws;                       // BR*NXC f16
  _Float16* u16  = xi16 + (size_t)BR * NXC;             // BR*NUC f16
  float* Hm = (float*)(u16 + (size_t)BR * NUC);         // 512*512
  float* NA = Hm + (size_t)NHC * NHC;                   // 256*768 augmented [P|Y|Z], ping
  float* NB = NA + (size_t)NXC * NAUG;                  // 256*768 pong
  unsigned int* dpkg = (unsigned int*)(NB + (size_t)NXC * NAUG);   // 128*256 u32
  _Float16* C1h  = (_Float16*)(dpkg + 128 * 256);
  _Float16* D12h = C1h + (size_t)NQC * NXC;
  _Float16* Ah   = D12h + (size_t)NQC * NUC;
  _Float16* B1h  = Ah + (size_t)NXC * NXC;
  _Float16* B2h  = B1h + (size_t)NXC * NQC;

  // setup: SYRKs + fused xi/u f16 convert in ONE launch (blocks 40.. do the cvt)
  syrk_mfma_kernel<<<40 + CVTB, 256, 0, stream>>>(Xin, Pstar, Hm, NA, xi, u, xi16, u16);
  derive_kernel<<<NXC, NXC, 0, stream>>>(Hm, Y1, Chi, D12, B2, NA, dpkg, C1h, D12h, B2h);

  // blocked Gauss-Jordan on augmented [P|Y|Z], 32-wide pivots, 128 blocks x 2 rows
  for (int kb = 0; kb < 8; ++kb) {
    const float* Nin = (kb & 1) ? NB : NA;
    float*      Nout = (kb & 1) ? NA : NB;
    gjstep_kernel<<<128, 256, 0, stream>>>(Nin, Nout, Ah, B1h, kb * 32);
  }

  // fully fused batch phase: v_base + w recurrence + xi_dot in one kernel
  wrec_fused_kernel<<<BR / 64, 256, 0, stream>>>(
      xi16, u16, C1h, D12h, bv, dpkg, Ah, B1h, B2h, bx, out);
}

// Round 19
// 250.397 us; speedup vs baseline: 3.2524x; 1.0020x over previous
//
#include <hip/hip_runtime.h>
#include <math.h>

#define NXC 256
#define NQC 256
#define NUC 64
#define NHC 512
#define BR  32768
#define EPSC 1e-3f
#define NAUG 768
#define CVTB 1536

typedef _Float16 h2_t __attribute__((ext_vector_type(2)));
typedef _Float16 f16x8 __attribute__((ext_vector_type(8)));
typedef float f32x4 __attribute__((ext_vector_type(4)));
union h2u { h2_t h; unsigned int u; };

__device__ __forceinline__ h2_t pk_f16(float a, float b) {
#if __has_builtin(__builtin_amdgcn_cvt_pkrtz)
  return __builtin_bit_cast(h2_t, __builtin_amdgcn_cvt_pkrtz(a, b));
#else
  h2_t r; r.x = (_Float16)a; r.y = (_Float16)b; return r;
#endif
}
__device__ __forceinline__ unsigned int pk_bits(float a, float b) { h2u x; x.h = pk_f16(a, b); return x.u; }
__device__ __forceinline__ h2_t b2h(unsigned int u) { h2u x; x.u = u; return x.h; }
__device__ __forceinline__ unsigned int h2b(h2_t v) { h2u x; x.h = v; return x.u; }

__device__ __forceinline__ float fdot2f(h2_t a, h2_t b, float c) {
#if __has_builtin(__builtin_amdgcn_fdot2)
  return __builtin_amdgcn_fdot2(a, b, c, false);
#else
  return c + (float)a.x * (float)b.x + (float)a.y * (float)b.y;
#endif
}

__device__ __forceinline__ float fast_tanh(float x) {
  float ax = fabsf(x);
  float e  = __expf(-2.0f * ax);
  float r  = __fdividef(1.0f - e, 1.0f + e);
  return copysignf(r, x);
}

__device__ __forceinline__ float fast_rcp(float x) {
#if __has_builtin(__builtin_amdgcn_rcpf)
  return __builtin_amdgcn_rcpf(x);
#else
  return 1.0f / x;
#endif
}

// in-register GJ inversion of a 32x32 block, one row per lane (lanes 0..31; 32..63
// mirror harmlessly). Verified rounds 9/14/15.
__device__ __forceinline__ void inv32_wave(float r[32], int ii) {
#pragma unroll
  for (int k = 0; k < 32; ++k) {
    float rk[32];
#pragma unroll
    for (int j = 0; j < 32; ++j) rk[j] = __shfl(r[j], k);
    float d = fast_rcp(rk[k]);
    float fik = r[k];
    if (ii == k) {
#pragma unroll
      for (int j = 0; j < 32; ++j) r[j] = (j == k) ? d : rk[j] * d;
    } else {
#pragma unroll
      for (int j = 0; j < 32; ++j) r[j] = (j == k) ? (-fik * d) : (r[j] - fik * (d * rk[j]));
    }
  }
}

// ---------------- H and P SYRKs via f16 MFMA + fused fp32->f16 batch convert -------
// Blocks 0..39: SYRK work. Blocks 40..: grid-stride convert of xi,u to f16.
__global__ __launch_bounds__(256) void syrk_mfma_kernel(const float* __restrict__ Xin,
                                                        const float* __restrict__ Pstar,
                                                        float* __restrict__ Hm,
                                                        float* __restrict__ Naug,
                                                        const float* __restrict__ xi,
                                                        const float* __restrict__ u,
                                                        _Float16* __restrict__ xi16,
                                                        _Float16* __restrict__ u16) {
  __shared__ _Float16 Alds[128][72];
  __shared__ _Float16 Blds[64][72];
  const int b = blockIdx.x, t = threadIdx.x;
  if (b >= 40) {
    const int nxi = BR * NXC / 8, ntot = nxi + BR * NUC / 8;
    int idx = (b - 40) * 256 + t;
    int stride = CVTB * 256;
    for (int i = idx; i < ntot; i += stride) {
      const float* s; _Float16* d; int j;
      if (i < nxi) { s = xi; d = xi16; j = i; } else { s = u; d = u16; j = i - nxi; }
      float4 a = ((const float4*)s)[(size_t)j * 2];
      float4 bb = ((const float4*)s)[(size_t)j * 2 + 1];
      uint4 o;
      o.x = pk_bits(a.x, a.y);  o.y = pk_bits(a.z, a.w);
      o.z = pk_bits(bb.x, bb.y); o.w = pk_bits(bb.z, bb.w);
      ((uint4*)d)[j] = o;
    }
    return;
  }
  const float* src; float* dst; int n, K; float scale; int rowbase, colbase;
  if (b < 32) { src = Xin;   dst = Hm;   n = NHC;  K = NHC; scale = 1.0f; rowbase = (b >> 3) * 128; colbase = (b & 7) * 64; }
  else { int b2 = b - 32; src = Pstar; dst = Naug; n = NAUG; K = NXC; scale = 0.5f; rowbase = (b2 >> 2) * 128; colbase = (b2 & 3) * 64; }
  const int r_a = t >> 1, h_a = t & 1;
  const int r_b = t >> 2, q_b = t & 3;
  const int lane = t & 63, wv = t >> 6;
  const int wm = wv >> 1, wn = wv & 1;
  const int l15 = lane & 15, l4 = lane >> 4;
  f32x4 acc[4][2] = {};
  for (int k0 = 0; k0 < K; k0 += 64) {
    uint4 av[4], bvv[2];
    {
      const float* p = src + (size_t)(rowbase + r_a) * K + k0 + h_a * 32;
#pragma unroll
      for (int m = 0; m < 4; m++) {
        float4 x0 = *(const float4*)(p + m * 8);
        float4 x1 = *(const float4*)(p + m * 8 + 4);
        uint4 pk;
        pk.x = pk_bits(x0.x, x0.y); pk.y = pk_bits(x0.z, x0.w);
        pk.z = pk_bits(x1.x, x1.y); pk.w = pk_bits(x1.z, x1.w);
        av[m] = pk;
      }
    }
    {
      const float* p = src + (size_t)(colbase + r_b) * K + k0 + q_b * 16;
      float4 x0 = *(const float4*)p,       x1 = *(const float4*)(p + 4);
      float4 x2 = *(const float4*)(p + 8), x3 = *(const float4*)(p + 12);
      bvv[0].x = pk_bits(x0.x, x0.y); bvv[0].y = pk_bits(x0.z, x0.w);
      bvv[0].z = pk_bits(x1.x, x1.y); bvv[0].w = pk_bits(x1.z, x1.w);
      bvv[1].x = pk_bits(x2.x, x2.y); bvv[1].y = pk_bits(x2.z, x2.w);
      bvv[1].z = pk_bits(x3.x, x3.y); bvv[1].w = pk_bits(x3.z, x3.w);
    }
    __syncthreads();
#pragma unroll
    for (int m = 0; m < 4; m++) *(uint4*)&Alds[r_a][h_a * 32 + m * 8] = av[m];
    *(uint4*)&Blds[r_b][q_b * 16]     = bvv[0];
    *(uint4*)&Blds[r_b][q_b * 16 + 8] = bvv[1];
    __syncthreads();
#pragma unroll
    for (int ks = 0; ks < 2; ks++) {
      f16x8 af[4], bf[2];
#pragma unroll
      for (int fm = 0; fm < 4; fm++)
        af[fm] = *(const f16x8*)&Alds[wm * 64 + fm * 16 + l15][ks * 32 + l4 * 8];
#pragma unroll
      for (int fn = 0; fn < 2; fn++)
        bf[fn] = *(const f16x8*)&Blds[wn * 32 + fn * 16 + l15][ks * 32 + l4 * 8];
#pragma unroll
      for (int fm = 0; fm < 4; fm++)
#pragma unroll
        for (int fn = 0; fn < 2; fn++)
          acc[fm][fn] = __builtin_amdgcn_mfma_f32_16x16x32_f16(af[fm], bf[fn], acc[fm][fn], 0, 0, 0);
    }
  }
#pragma unroll
  for (int fm = 0; fm < 4; fm++)
#pragma unroll
    for (int fn = 0; fn < 2; fn++) {
      int col = colbase + wn * 32 + fn * 16 + l15;
      f32x4 a = acc[fm][fn];
#pragma unroll
      for (int reg = 0; reg < 4; reg++) {
        int row = rowbase + wm * 64 + fm * 16 + l4 * 4 + reg;
        float val = scale * a[reg] + ((row == col) ? EPSC : 0.f);
        dst[(size_t)row * n + col] = val;
      }
    }
}

// ---------------- derived small matrices (+ f16 weights + packed D11 pairs) --------
__global__ __launch_bounds__(256) void derive_kernel(const float* __restrict__ H,
                                                     const float* __restrict__ Y1,
                                                     const float* __restrict__ Chi,
                                                     const float* __restrict__ D12,
                                                     const float* __restrict__ B2,
                                                     float* __restrict__ Naug,
                                                     unsigned int* __restrict__ dpk_g,
                                                     _Float16* __restrict__ C1h,
                                                     _Float16* __restrict__ D12h,
                                                     _Float16* __restrict__ B2h) {
  int i = blockIdx.x, j = threadIdx.x;
  float li = 2.0f / H[(size_t)(NXC + i) * NHC + NXC + i];
  Naug[(size_t)i * NAUG + NXC + j]     = -0.5f * (H[(size_t)i * NHC + j] + Y1[i * NXC + j] - Y1[j * NXC + i]);
  C1h[i * NXC + j] = (_Float16)(li * Chi[j * NQC + i]);
  Naug[(size_t)i * NAUG + 2 * NXC + j] = -H[(size_t)i * NHC + NXC + j] - Chi[i * NQC + j];
  float dv = (j < i) ? (-li * H[(size_t)(NXC + i) * NHC + NXC + j]) : 0.f;
  float dhi = __shfl_xor(dv, 1);
  if ((j & 1) == 0) dpk_g[(size_t)(j >> 1) * NXC + i] = pk_bits(dv, dhi);
  if (j < NUC) {
    D12h[i * NUC + j] = (_Float16)D12[i * NUC + j];
    B2h[i * NUC + j]  = (_Float16)B2[i * NUC + j];
  }
}

// ---------------- GJ step v2: 128 blocks x 2 rows, coef prefetch (r13-verified) ----
__global__ __launch_bounds__(256) void gjstep_kernel(const float* __restrict__ Nin,
                                                     float* __restrict__ Nout,
                                                     _Float16* __restrict__ Ah,
                                                     _Float16* __restrict__ B1h,
                                                     int k0) {
  __shared__ float Dl[32][33];
  __shared__ float cfl[2][33];
  const int t = threadIdx.x;
  const int row0 = blockIdx.x * 2;
  const bool last = (k0 + 32 == NXC);
  // coef threads (64..127) prefetch their row's f-vector while wave0 inverts
  const bool docoef = (t >= 64 && t < 128);
  const int crr = (t - 64) >> 5, cs = t & 31;
  const int ci = row0 + crr;
  const bool cpiv = (ci >= k0 && ci < k0 + 32);
  float fv[32];
  if (docoef && !cpiv) {
#pragma unroll
    for (int q = 0; q < 32; ++q) fv[q] = Nin[(size_t)ci * NAUG + k0 + q];
  }
  if (t < 64) {
    const int ii = t & 31;
    float r[32];
#pragma unroll
    for (int j = 0; j < 32; ++j) r[j] = Nin[(size_t)(k0 + ii) * NAUG + k0 + j];
    inv32_wave(r, ii);
    if (t < 32) {
#pragma unroll
      for (int j = 0; j < 32; ++j) Dl[ii][j] = r[j];
    }
  }
  __syncthreads();
  if (docoef) {
    float c;
    if (cpiv) {
      c = Dl[ci - k0][cs];
    } else {
      float g = 0.f;
#pragma unroll
      for (int q = 0; q < 32; ++q) g = fmaf(fv[q], Dl[q][cs], g);
      c = -g;
    }
    cfl[crr][cs] = c;
  }
  __syncthreads();
  const int rr = t >> 7;                  // 0..1 (128 threads per row)
  const int i = row0 + rr;
  const bool piv = (i >= k0 && i < k0 + 32);
  float cf[32];
#pragma unroll
  for (int s = 0; s < 32; ++s) cf[s] = cfl[rr][s];
  const int c40 = (k0 + 32) >> 2;
  for (int c4 = c40 + (t & 127); c4 < (NAUG >> 2); c4 += 128) {
    float4 acc;
    if (piv) { acc.x = 0.f; acc.y = 0.f; acc.z = 0.f; acc.w = 0.f; }
    else     { acc = *(const float4*)&Nin[(size_t)i * NAUG + c4 * 4]; }
#pragma unroll
    for (int s = 0; s < 32; ++s) {
      float4 pv = *(const float4*)&Nin[(size_t)(k0 + s) * NAUG + c4 * 4];
      acc.x = fmaf(cf[s], pv.x, acc.x);
      acc.y = fmaf(cf[s], pv.y, acc.y);
      acc.z = fmaf(cf[s], pv.z, acc.z);
      acc.w = fmaf(cf[s], pv.w, acc.w);
    }
    if (!last) {
      *(float4*)&Nout[(size_t)i * NAUG + c4 * 4] = acc;
    } else {
      int cc = c4 * 4 - NXC;  // 0..511 within [A | B1]
      h2_t h0, h1;
      h0.x = (_Float16)acc.x; h0.y = (_Float16)acc.y;
      h1.x = (_Float16)acc.z; h1.y = (_Float16)acc.w;
      uint2 o; o.x = h2b(h0); o.y = h2b(h1);
      if (cc < NXC) *(uint2*)&Ah[(size_t)i * NXC + cc]          = o;
      else          *(uint2*)&B1h[(size_t)i * NXC + (cc - NXC)] = o;
    }
  }
}

// ======== wrec v20: r13 body + per-thread-quad serial tri-dot =====================
// Thread s (of the 4 sharing a row) owns ONLY pairs 4s..4s+3 in wq[0..3] -- every
// access statically indexed (rule #20; r16's runtime wpk[s*4+j] demoted to scratch).
// At unrolled iteration i, slot (i>>1)&3 and owner i>>3 are compile-time; ownership
// write is one cndmask. Stale pairs from earlier kb are masked by derive's zero
// coefficients (dv=0 for j>=i), identical to the r13 masking. 4-lane shfl reduce.
__global__ __launch_bounds__(256, 2) void wrec_fused_kernel(
    const _Float16* __restrict__ xi16, const _Float16* __restrict__ u16,
    const _Float16* __restrict__ C1h, const _Float16* __restrict__ D12h,
    const float* __restrict__ bv, const unsigned int* __restrict__ dpk_g,
    const _Float16* __restrict__ Ah, const _Float16* __restrict__ B1h,
    const _Float16* __restrict__ B2h, const float* __restrict__ bx,
    float* __restrict__ out) {
  __shared__ unsigned int pool[14976];            // 59904 B
  unsigned int* wlds  = pool;                     // 64*132 u32 (w f16 pairs)
  unsigned int* dpkT  = pool + 8448;              // 32*116
  unsigned int* tript = pool + 12160;             // 32*16
  float*        vbuf  = (float*)(pool + 12672);   // 64*36

  const int t = threadIdx.x;
  const int r = t >> 2, s = t & 3;
  const int lane = t & 63, w = t >> 6;
  const int l15 = lane & 15, l4 = lane >> 4;
  const size_t rowbase = (size_t)blockIdx.x * 64;
  const _Float16* wl16 = (const _Float16*)wlds;

  // preload this wave's xi/u A-fragments (rows w*16 + l15)
  f16x8 xi_frag[8], u_frag[2];
  {
    const _Float16* px = xi16 + (rowbase + w * 16 + l15) * NXC + l4 * 8;
#pragma unroll
    for (int kc = 0; kc < 8; ++kc) xi_frag[kc] = *(const f16x8*)(px + kc * 32);
    const _Float16* pu = u16 + (rowbase + w * 16 + l15) * NUC + l4 * 8;
#pragma unroll
    for (int kc = 0; kc < 2; ++kc) u_frag[kc] = *(const f16x8*)(pu + kc * 32);
  }

  h2_t wq[4];   // this thread's quad: pairs 4s..4s+3 (w indices 8s..8s+7)
#pragma unroll
  for (int p = 0; p < 4; ++p) wq[p] = pk_f16(0.f, 0.f);

  for (int kb = 0; kb < 8; ++kb) {
    const int i0 = kb * 32;
    for (int idx = t; idx < (i0 >> 1) * 32; idx += 256) {
      int cc = idx & 31, jp = idx >> 5;
      dpkT[cc * 116 + jp] = dpk_g[(size_t)jp * NXC + i0 + cc];
    }
    if (t < 128) {
      int jp = t >> 3, iq = t & 7;
      uint4 d4 = *(const uint4*)&dpk_g[(size_t)(i0 / 2 + jp) * NXC + i0 + iq * 4];
      tript[(iq * 4 + 0) * 16 + jp] = d4.x;
      tript[(iq * 4 + 1) * 16 + jp] = d4.y;
      tript[(iq * 4 + 2) * 16 + jp] = d4.z;
      tript[(iq * 4 + 3) * 16 + jp] = d4.w;
    }
    // v_base: acc = bv + xi@C1^T + u@D12^T (per-wave, fp32 kept)
    f32x4 acc0, acc1;
    {
      float b0 = bv[i0 + l15], b1 = bv[i0 + 16 + l15];
      acc0[0] = b0; acc0[1] = b0; acc0[2] = b0; acc0[3] = b0;
      acc1[0] = b1; acc1[1] = b1; acc1[2] = b1; acc1[3] = b1;
#pragma unroll
      for (int kc = 0; kc < 8; ++kc) {
        f16x8 bf0 = *(const f16x8*)&C1h[(size_t)(i0 + l15) * NXC + kc * 32 + l4 * 8];
        f16x8 bf1 = *(const f16x8*)&C1h[(size_t)(i0 + 16 + l15) * NXC + kc * 32 + l4 * 8];
        acc0 = __builtin_amdgcn_mfma_f32_16x16x32_f16(xi_frag[kc], bf0, acc0, 0, 0, 0);
        acc1 = __builtin_amdgcn_mfma_f32_16x16x32_f16(xi_frag[kc], bf1, acc1, 0, 0, 0);
      }
#pragma unroll
      for (int kc = 0; kc < 2; ++kc) {
        f16x8 bf0 = *(const f16x8*)&D12h[(size_t)(i0 + l15) * NUC + kc * 32 + l4 * 8];
        f16x8 bf1 = *(const f16x8*)&D12h[(size_t)(i0 + 16 + l15) * NUC + kc * 32 + l4 * 8];
        acc0 = __builtin_amdgcn_mfma_f32_16x16x32_f16(u_frag[kc], bf0, acc0, 0, 0, 0);
        acc1 = __builtin_amdgcn_mfma_f32_16x16x32_f16(u_frag[kc], bf1, acc1, 0, 0, 0);
      }
    }
    __syncthreads();

    // cross terms from previous kb blocks
    for (int ks = 0; ks < kb; ++ks) {
      f16x8 af = *(const f16x8*)&wl16[(size_t)(w * 16 + l15) * 264 + ks * 32 + l4 * 8];
      uint4 b0 = *(const uint4*)&dpkT[(l15) * 116 + ks * 16 + l4 * 4];
      uint4 b1 = *(const uint4*)&dpkT[(16 + l15) * 116 + ks * 16 + l4 * 4];
      acc0 = __builtin_amdgcn_mfma_f32_16x16x32_f16(af, __builtin_bit_cast(f16x8, b0), acc0, 0, 0, 0);
      acc1 = __builtin_amdgcn_mfma_f32_16x16x32_f16(af, __builtin_bit_cast(f16x8, b1), acc1, 0, 0, 0);
    }

#pragma unroll
    for (int reg = 0; reg < 4; ++reg) {
      int rowm = w * 16 + l4 * 4 + reg;
      vbuf[rowm * 36 + l15]      = acc0[reg];
      vbuf[rowm * 36 + 16 + l15] = acc1[reg];
    }

    float wprev = 0.f;
#pragma unroll
    for (int i = 0; i < 32; ++i) {
      const int npairs = (i + 1) >> 1;
      const int nq = (npairs + 3) >> 2;
      float td = 0.f;
      if (s < nq) {
        uint4 tq = *(const uint4*)&tript[i * 16 + s * 4];
        float t0 = 0.f, t1 = 0.f;
        t0 = fdot2f(wq[0], b2h(tq.x), t0);
        t1 = fdot2f(wq[1], b2h(tq.y), t1);
        t0 = fdot2f(wq[2], b2h(tq.z), t0);
        t1 = fdot2f(wq[3], b2h(tq.w), t1);
        td = t0 + t1;
      }
      td += __shfl_xor(td, 1);
      td += __shfl_xor(td, 2);
      float vi = vbuf[r * 36 + i];
      float wi = fast_tanh(vi + td);
      h2_t np;
      if ((i & 1) == 0) { wprev = wi; np = pk_f16(wi, 0.f); }
      else              { np = pk_f16(wprev, wi); }
      wq[(i >> 1) & 3] = (s == (i >> 3)) ? np : wq[(i >> 1) & 3];
    }

    {
      uint4 o;
      o.x = h2b(wq[0]); o.y = h2b(wq[1]);
      o.z = h2b(wq[2]); o.w = h2b(wq[3]);
      *(uint4*)&wlds[r * 132 + kb * 16 + s * 4] = o;
    }
    __syncthreads();
  }

  // ---- final fused GEMM: out = xi@Ah^T + w@B1h^T + u@B2h^T + bx ----
  _Float16* Ws = (_Float16*)dpkT;
  f32x4 oacc[16];
#pragma unroll
  for (int ct = 0; ct < 16; ++ct) {
    float bb = bx[ct * 16 + l15];
    oacc[ct][0] = bb; oacc[ct][1] = bb; oacc[ct][2] = bb; oacc[ct][3] = bb;
  }
  uint4 pa, pb, pc, pd;
  {
    const _Float16* p = Ah + (size_t)t * NXC;   // rr=0: Ah, kc=0
    pa = *(const uint4*)p;        pb = *(const uint4*)(p + 8);
    pc = *(const uint4*)(p + 16); pd = *(const uint4*)(p + 24);
  }
#pragma unroll
  for (int rr = 0; rr < 18; ++rr) {
    const int sel = rr < 8 ? 0 : (rr < 16 ? 1 : 2);
    const int kc  = sel == 0 ? rr : (sel == 1 ? rr - 8 : rr - 16);
    __syncthreads();                       // readers of previous chunk done
    *(uint4*)&Ws[t * 40]      = pa;
    *(uint4*)&Ws[t * 40 + 8]  = pb;
    *(uint4*)&Ws[t * 40 + 16] = pc;
    *(uint4*)&Ws[t * 40 + 24] = pd;
    __syncthreads();                       // chunk visible
    if (rr < 17) {                         // T14: issue next chunk early
      const int rs = rr + 1;
      const int s2 = rs < 8 ? 0 : (rs < 16 ? 1 : 2);
      const int k2 = s2 == 0 ? rs : (s2 == 1 ? rs - 8 : rs - 16);
      const _Float16* Wp = s2 == 0 ? Ah : (s2 == 1 ? B1h : B2h);
      const int KK = (s2 == 2) ? NUC : NXC;
      const _Float16* p = Wp + (size_t)t * KK + k2 * 32;
      pa = *(const uint4*)p;        pb = *(const uint4*)(p + 8);
      pc = *(const uint4*)(p + 16); pd = *(const uint4*)(p + 24);
    }
    f16x8 af;
    if (sel == 0)      af = xi_frag[kc];
    else if (sel == 1) af = *(const f16x8*)&wl16[(size_t)(w * 16 + l15) * 264 + kc * 32 + l4 * 8];
    else               af = u_frag[kc];
#pragma unroll
    for (int ct = 0; ct < 16; ++ct) {
      f16x8 bf = *(const f16x8*)&Ws[(ct * 16 + l15) * 40 + l4 * 8];
      oacc[ct] = __builtin_amdgcn_mfma_f32_16x16x32_f16(af, bf, oacc[ct], 0, 0, 0);
    }
  }
#pragma unroll
  for (int ct = 0; ct < 16; ++ct) {
#pragma unroll
    for (int reg = 0; reg < 4; ++reg) {
      int row = (int)rowbase + w * 16 + l4 * 4 + reg;
      out[(size_t)row * NXC + ct * 16 + l15] = oacc[ct][reg];
    }
  }
}

extern "C" void kernel_launch(void* const* d_in, const int* in_sizes, int n_in,
                              void* d_out, int out_size, void* d_ws, size_t ws_size,
                              hipStream_t stream) {
  (void)in_sizes; (void)n_in; (void)out_size; (void)ws_size;
  const float* xi    = (const float*)d_in[1];
  const float* u     = (const float*)d_in[2];
  const float* Pstar = (const float*)d_in[3];
  const float* Chi   = (const float*)d_in[4];
  const float* Y1    = (const float*)d_in[5];
  const float* B2    = (const float*)d_in[6];
  const float* D12   = (const float*)d_in[7];
  const float* Xin   = (const float*)d_in[8];
  const float* bx    = (const float*)d_in[9];
  const float* bv    = (const float*)d_in[10];
  float* out = (float*)d_out;

  float* ws = (float*)d_ws;
  _Float16* xi16 = (_Float16*)ws;                       // BR*NXC f16
  _Float16* u16  = xi16 + (size_t)BR * NXC;             // BR*NUC f16
  float* Hm = (float*)(u16 + (size_t)BR * NUC);         // 512*512
  float* NA = Hm + (size_t)NHC * NHC;                   // 256*768 augmented [P|Y|Z], ping
  float* NB = NA + (size_t)NXC * NAUG;                  // 256*768 pong
  unsigned int* dpkg = (unsigned int*)(NB + (size_t)NXC * NAUG);   // 128*256 u32
  _Float16* C1h  = (_Float16*)(dpkg + 128 * 256);
  _Float16* D12h = C1h + (size_t)NQC * NXC;
  _Float16* Ah   = D12h + (size_t)NQC * NUC;
  _Float16* B1h  = Ah + (size_t)NXC * NXC;
  _Float16* B2h  = B1h + (size_t)NXC * NQC;

  // setup: SYRKs + fused xi/u f16 convert in ONE launch (blocks 40.. do the cvt)
  syrk_mfma_kernel<<<40 + CVTB, 256, 0, stream>>>(Xin, Pstar, Hm, NA, xi, u, xi16, u16);
  derive_kernel<<<NXC, NXC, 0, stream>>>(Hm, Y1, Chi, D12, B2, NA, dpkg, C1h, D12h, B2h);

  // blocked Gauss-Jordan on augmented [P|Y|Z], 32-wide pivots, 128 blocks x 2 rows
  for (int kb = 0; kb < 8; ++kb) {
    const float* Nin = (kb & 1) ? NB : NA;
    float*      Nout = (kb & 1) ? NA : NB;
    gjstep_kernel<<<128, 256, 0, stream>>>(Nin, Nout, Ah, B1h, kb * 32);
  }

  // fully fused batch phase: v_base + w recurrence + xi_dot in one kernel
  wrec_fused_kernel<<<BR / 64, 256, 0, stream>>>(
      xi16, u16, C1h, D12h, bv, dpkg, Ah, B1h, B2h, bx, out);
}